// Round 11
// baseline (54.925 us; speedup 1.0000x reference)
//
#include <hip/hip_runtime.h>
#include <float.h>
#include <math.h>

#define NB 8192      // batch
#define NC 128       // classes
#define NT 64        // time steps
#define ACE_EPS 1e-5f

typedef float f32x4 __attribute__((ext_vector_type(4)));

// workspace layout:
//   [0,    32KB)   prefix[NB] (int)
//   [32KB, 64KB)   loss[NB]   (float)

// ---------------------------------------------------------------------------
// 0) exclusive prefix sum of target_lengths — single 1024-thread block.
// ---------------------------------------------------------------------------
__global__ __launch_bounds__(1024) void prefix_kernel(
    const int* __restrict__ lens, int* __restrict__ prefix) {
  const int tid = threadIdx.x;
  const int lane = tid & 63;
  const int wid = tid >> 6;          // 16 waves

  int4 v[2];
  const int4* l4 = (const int4*)lens + tid * 2;   // 8 ints per thread
  v[0] = l4[0]; v[1] = l4[1];
  const int s = v[0].x + v[0].y + v[0].z + v[0].w +
                v[1].x + v[1].y + v[1].z + v[1].w;

  int scan = s;
#pragma unroll
  for (int off = 1; off < 64; off <<= 1) {
    int t = __shfl_up(scan, off, 64);
    if (lane >= off) scan += t;
  }
  __shared__ int wsum[16];
  if (lane == 63) wsum[wid] = scan;
  __syncthreads();
  int wbase = 0;
  for (int w = 0; w < wid; ++w) wbase += wsum[w];

  int run = wbase + scan - s;        // exclusive prefix of this thread's 8
  int4 o[2];
#pragma unroll
  for (int i = 0; i < 2; ++i) {
    const int a = run;
    const int b2 = a + v[i].x;
    const int c2 = b2 + v[i].y;
    const int d2 = c2 + v[i].z;
    o[i] = make_int4(a, b2, c2, d2);
    run = d2 + v[i].w;
  }
  int4* p4 = (int4*)prefix + tid * 2;
  p4[0] = o[0]; p4[1] = o[1];
}

// ---------------------------------------------------------------------------
// A) fused streaming argmax + ACE loss (R10 structure — no LDS, no atomics,
//    no barrier: barrier/atomic tails collapse the allocation to 32 VGPR and
//    serialize the stream; R2/R6/R8 evidence).
//    R11 change: x loads are NONTEMPORAL (nt, no-allocate) — x has zero
//    intra-dispatch reuse, so cache allocation is pure overhead; tests
//    whether the 5.3 TB/s plateau is the cache-allocation path.
// ---------------------------------------------------------------------------
__global__ __launch_bounds__(256, 8) void ace_fused_kernel(
    const float* __restrict__ x, const int* __restrict__ y,
    const int* __restrict__ lens, const int* __restrict__ prefix,
    float* __restrict__ loss_out) {
  const int wave = threadIdx.x >> 6;
  const int lane = threadIdx.x & 63;
  const int b = blockIdx.x * 4 + wave;
  const int crow = lane >> 4;

  // ---- hoisted tail inputs (latency hides under the x stream) ----
  const int len = lens[b];
  const int start = prefix[b];
  const int yv = (lane < len) ? y[start + lane] : -1;

  // ---- streaming argmax: 32 coalesced nontemporal float4 loads ----
  const f32x4* xv = (const f32x4*)(x + (size_t)b * (NC * NT)) + lane;
  float mv[4];
  int am[4];
#pragma unroll
  for (int j = 0; j < 4; ++j) { mv[j] = -FLT_MAX; am[j] = 0; }

#pragma unroll 8
  for (int cc = 0; cc < 32; ++cc) {
    const int c = cc * 4 + crow;
    f32x4 v = __builtin_nontemporal_load(xv + cc * 64);
#pragma unroll
    for (int j = 0; j < 4; ++j) {
      if (v[j] > mv[j]) { mv[j] = v[j]; am[j] = c; }   // strict > : first max
    }
  }

  // combine across the 4 lanes (crow dim) sharing one t-group; min idx on tie
#pragma unroll
  for (int j = 0; j < 4; ++j) {
#pragma unroll
    for (int off = 16; off < 64; off <<= 1) {
      float om = __shfl_xor(mv[j], off, 64);
      int oa = __shfl_xor(am[j], off, 64);
      if (om > mv[j] || (om == mv[j] && oa < am[j])) { mv[j] = om; am[j] = oa; }
    }
  }
  int my_am = am[0];
  if (crow == 1) my_am = am[1];
  if (crow == 2) my_am = am[2];
  if (crow == 3) my_am = am[3];

  // ---- ballot/popcount loss tail (lane l owns t = 4*(l&15)+(l>>4)) ----
  int ns = 0;
  for (int i = 0; i < len; ++i) {
    const int c = __shfl(yv, i, 64);
    const unsigned long long baly = __ballot(lane < len && yv == c);
    const int nkc = __popcll(__ballot(my_am == c));
    if ((int)__ffsll(baly) - 1 == i) ns += nkc;   // uniform: first occurrence
  }
  const float inv_ns = (ns > 0) ? (1.0f / (float)ns) : 0.0f;
  const float inv_ys = 1.0f / (float)len;         // y_sum == len
  float a = 0.0f;
  for (int i = 0; i < len; ++i) {
    const int c = __shfl(yv, i, 64);
    const unsigned long long baly = __ballot(lane < len && yv == c);
    if ((int)__ffsll(baly) - 1 == i) {            // uniform branch
      const int nkc = __popcll(__ballot(my_am == c));
      const int ykc = __popcll(baly);
      const float np = (ns == 0) ? ACE_EPS : fmaxf((float)nkc * inv_ns, ACE_EPS);
      a -= np * logf((float)ykc * inv_ys);
    }
  }
  if (lane == 0) loss_out[b] = a;
}

// ---------------------------------------------------------------------------
// C) deterministic mean — single 512-thread block, float4 loads,
//    shuffle-reduce. Fixed order -> deterministic.
// ---------------------------------------------------------------------------
__global__ __launch_bounds__(512) void reduce_kernel(
    const float* __restrict__ loss, float* __restrict__ out) {
  const int tid = threadIdx.x;
  const int lane = tid & 63;
  const int wid = tid >> 6;          // 8 waves
  const float4* l4 = (const float4*)loss;   // 2048 float4

  float a = 0.0f;
#pragma unroll
  for (int i = 0; i < 4; ++i) {
    float4 v = l4[tid + i * 512];
    a += v.x + v.y + v.z + v.w;
  }
#pragma unroll
  for (int off = 1; off < 64; off <<= 1) a += __shfl_xor(a, off, 64);

  __shared__ float ws[8];
  if (lane == 0) ws[wid] = a;
  __syncthreads();
  if (tid == 0) {
    float s = 0.0f;
#pragma unroll
    for (int w = 0; w < 8; ++w) s += ws[w];
    out[0] = s / (float)NB;
  }
}

extern "C" void kernel_launch(void* const* d_in, const int* in_sizes, int n_in,
                              void* d_out, int out_size, void* d_ws, size_t ws_size,
                              hipStream_t stream) {
  const float* x = (const float*)d_in[0];          // [B, C, T] f32
  const int* y = (const int*)d_in[1];              // [B*L] i32
  const int* lens = (const int*)d_in[2];           // [B] i32
  float* out = (float*)d_out;                      // scalar f32

  int* prefix = (int*)d_ws;                                      // 32 KB
  float* loss = (float*)((char*)d_ws + 32 * 1024);               // 32 KB

  prefix_kernel<<<1, 1024, 0, stream>>>(lens, prefix);
  ace_fused_kernel<<<NB / 4, 256, 0, stream>>>(x, y, lens, prefix, loss);
  reduce_kernel<<<1, 512, 0, stream>>>(loss, out);
}